// Round 1
// baseline (4964.685 us; speedup 1.0000x reference)
//
#include <hip/hip_runtime.h>

#define N_NODE 100000
#define EMB 112
#define BATCH 512
#define SEQL 50
#define NNZ 1600000

// ---------------- HyperConv: one sparse layer, scatter-add with atomics ----
// out[rows[e]] += vals[e] * src[cols[e]]   for all e
// One thread per (edge, float4-chunk): 28 chunks of 4 floats = 112 features.
__global__ __launch_bounds__(256) void spmm_scatter(
    const float* __restrict__ src, const float* __restrict__ vals,
    const int* __restrict__ rows, const int* __restrict__ cols,
    float* __restrict__ out)
{
    int idx = blockIdx.x * 256 + threadIdx.x;
    if (idx >= NNZ * 28) return;
    int e = idx / 28;
    int c = idx - e * 28;
    int col = cols[e];
    int row = rows[e];
    float v = vals[e];
    const float4 x = ((const float4*)(src + (size_t)col * EMB))[c];
    float* o = out + (size_t)row * EMB + (size_t)c * 4;
    atomicAdd(o + 0, v * x.x);
    atomicAdd(o + 1, v * x.y);
    atomicAdd(o + 2, v * x.z);
    atomicAdd(o + 3, v * x.w);
}

// ---------------- Fused SR_IEM attention pooling ---------------------------
// One block per batch element. seq/Q/K live in LDS (stride padded to 113).
#define PAD 113
__global__ __launch_bounds__(256) void attention_pool(
    const float* __restrict__ emb0, const float* __restrict__ emb1,
    const float* __restrict__ emb2,
    const float* __restrict__ Wq, const float* __restrict__ Wk,
    const int* __restrict__ session_item, const int* __restrict__ session_len,
    const float* __restrict__ mask,
    float* __restrict__ seq_h, float* __restrict__ acc2)
{
    __shared__ float s_seq[SEQL][PAD];
    __shared__ float s_Q[SEQL][PAD];
    __shared__ float s_K[SEQL][PAD];
    __shared__ float s_alpha[SEQL];
    __shared__ float s_beta[SEQL];

    const int b = blockIdx.x;
    const int tid = threadIdx.x;

    // gather seq[b] = cl[session_item[b]]; item_emb = (e0+e1+e2)/3, cl[0]=0
    for (int idx = tid; idx < SEQL * EMB; idx += 256) {
        int l = idx / EMB, d = idx - l * EMB;
        int g = session_item[b * SEQL + l];
        float v = 0.f;
        if (g > 0) {
            size_t off = (size_t)(g - 1) * EMB + d;
            v = (emb0[off] + emb1[off] + emb2[off]) * (1.f / 3.f);
        }
        s_seq[l][d] = v;
    }
    if (tid < SEQL) s_alpha[tid] = 0.f;
    __syncthreads();

    // Q = sigmoid(seq @ Wq), K = sigmoid(seq @ Wk)
    for (int idx = tid; idx < SEQL * EMB; idx += 256) {
        int l = idx / EMB, e = idx - l * EMB;
        float q = 0.f, k = 0.f;
        for (int d = 0; d < EMB; ++d) {
            float sv = s_seq[l][d];
            q += sv * Wq[d * EMB + e];
            k += sv * Wk[d * EMB + e];
        }
        s_Q[l][e] = 1.f / (1.f + __expf(-q));
        s_K[l][e] = 1.f / (1.f + __expf(-k));
    }
    __syncthreads();

    // alpha[l] = sum_m sigmoid(Q[l].K[m])/sqrt(d) * mask * offdiag
    const float inv_sqrt_d = rsqrtf((float)EMB);
    for (int idx = tid; idx < SEQL * SEQL; idx += 256) {
        int m = idx / SEQL, l = idx - m * SEQL;   // l fastest -> lanes hit distinct l
        if (l == m) continue;
        if (mask[b * SEQL + l] == 0.f || mask[b * SEQL + m] == 0.f) continue;
        float dot = 0.f;
        for (int d = 0; d < EMB; ++d) dot += s_Q[l][d] * s_K[m][d];
        float c = inv_sqrt_d / (1.f + __expf(-dot));
        atomicAdd(&s_alpha[l], c);
    }
    __syncthreads();

    // beta = masked softmax(alpha / session_len) over l  (wave 0, lanes=l)
    if (tid < 64) {
        float slen = (float)session_len[b];
        float a = (tid < SEQL && mask[b * SEQL + tid] > 0.f)
                      ? s_alpha[tid] / slen : -1e30f;
        float mx = a;
        for (int o = 32; o > 0; o >>= 1) mx = fmaxf(mx, __shfl_xor(mx, o));
        float ex = __expf(a - mx);          // invalid lanes underflow to 0
        float sm = ex;
        for (int o = 32; o > 0; o >>= 1) sm += __shfl_xor(sm, o);
        if (tid < SEQL) s_beta[tid] = ex / sm;
    }
    __syncthreads();

    // seq_h[b] = sum_l beta[l] * seq[l];  acc2 init = seq_h
    for (int d = tid; d < EMB; d += 256) {
        float h = 0.f;
        for (int l = 0; l < SEQL; ++l) h += s_beta[l] * s_seq[l][d];
        seq_h[b * EMB + d] = h;
        acc2[b * EMB + d] = h;
    }
}

// ---------------- DA = D @ A  (512x512x512, naive coalesced) ---------------
__global__ __launch_bounds__(256) void gemm_DA(
    const float* __restrict__ D, const float* __restrict__ A,
    float* __restrict__ DA)
{
    int j = blockIdx.x * 256 + threadIdx.x;
    int i = blockIdx.y;
    float acc = 0.f;
    for (int k = 0; k < BATCH; ++k) acc += D[i * BATCH + k] * A[k * BATCH + j];
    DA[i * BATCH + j] = acc;
}

// ---------------- t = s @ W^T  ([512,112] x [112,112]^T) -------------------
__global__ __launch_bounds__(128) void sess_linear(
    const float* __restrict__ s, const float* __restrict__ W,
    float* __restrict__ t)
{
    __shared__ float s_row[EMB];
    int b = blockIdx.x;
    int e = threadIdx.x;
    if (e < EMB) s_row[e] = s[b * EMB + e];
    __syncthreads();
    if (e >= EMB) return;
    float acc = 0.f;
    for (int d = 0; d < EMB; ++d) acc += s_row[d] * W[e * EMB + d];
    t[b * EMB + e] = acc;
}

// ---------------- s = DA @ t; acc2 += s/||s||; optionally out = acc2/3 -----
__global__ __launch_bounds__(128) void sess_prop(
    const float* __restrict__ DA, const float* __restrict__ t,
    float* __restrict__ s_out, float* __restrict__ acc2,
    float* __restrict__ out, int is_last)
{
    __shared__ float s_da[BATCH];
    __shared__ float s_sq[128];
    int b = blockIdx.x;
    int e = threadIdx.x;
    for (int k = e; k < BATCH; k += 128) s_da[k] = DA[b * BATCH + k];
    __syncthreads();

    float v = 0.f;
    if (e < EMB) {
        for (int k = 0; k < BATCH; ++k) v += s_da[k] * t[k * EMB + e];
    }
    s_sq[e] = (e < EMB) ? v * v : 0.f;
    __syncthreads();
    for (int off = 64; off > 0; off >>= 1) {
        if (e < off) s_sq[e] += s_sq[e + off];
        __syncthreads();
    }
    float nrm = fmaxf(sqrtf(s_sq[0]), 1e-12f);
    if (e < EMB) {
        float a = acc2[b * EMB + e] + v / nrm;
        acc2[b * EMB + e] = a;
        s_out[b * EMB + e] = v;
        if (is_last) out[b * EMB + e] = a * (1.f / 3.f);
    }
}

extern "C" void kernel_launch(void* const* d_in, const int* in_sizes, int n_in,
                              void* d_out, int out_size, void* d_ws, size_t ws_size,
                              hipStream_t stream)
{
    (void)in_sizes; (void)n_in; (void)out_size; (void)ws_size;

    const float* embedding    = (const float*)d_in[0];
    const float* adj_vals     = (const float*)d_in[1];
    const float* W_q          = (const float*)d_in[2];
    const float* W_k          = (const float*)d_in[3];
    const float* w_sess       = (const float*)d_in[4];
    const float* D            = (const float*)d_in[5];
    const float* A            = (const float*)d_in[6];
    const int*   adj_rows     = (const int*)d_in[7];
    const int*   adj_cols     = (const int*)d_in[8];
    const int*   session_item = (const int*)d_in[9];
    const int*   session_len  = (const int*)d_in[10];
    const float* mask         = (const float*)d_in[11];
    float* out = (float*)d_out;

    // workspace layout (fp32): emb1 | emb2 | DA | seqh | acc2 | tbuf | sbuf
    float* emb1 = (float*)d_ws;
    float* emb2 = emb1 + (size_t)N_NODE * EMB;
    float* DAb  = emb2 + (size_t)N_NODE * EMB;
    float* seqh = DAb  + (size_t)BATCH * BATCH;
    float* acc2 = seqh + (size_t)BATCH * EMB;
    float* tbuf = acc2 + (size_t)BATCH * EMB;
    float* sbuf = tbuf + (size_t)BATCH * EMB;

    hipMemsetAsync(emb1, 0, (size_t)2 * N_NODE * EMB * sizeof(float), stream);

    const int spmm_work = NNZ * 28;
    const int spmm_grid = (spmm_work + 255) / 256;
    spmm_scatter<<<spmm_grid, 256, 0, stream>>>(embedding, adj_vals, adj_rows, adj_cols, emb1);
    spmm_scatter<<<spmm_grid, 256, 0, stream>>>(emb1,      adj_vals, adj_rows, adj_cols, emb2);

    attention_pool<<<BATCH, 256, 0, stream>>>(embedding, emb1, emb2, W_q, W_k,
                                              session_item, session_len, mask,
                                              seqh, acc2);

    gemm_DA<<<dim3(BATCH / 256, BATCH), 256, 0, stream>>>(D, A, DAb);

    // layer 0
    sess_linear<<<BATCH, 128, 0, stream>>>(seqh, w_sess + 0 * EMB * EMB, tbuf);
    sess_prop  <<<BATCH, 128, 0, stream>>>(DAb, tbuf, sbuf, acc2, out, 0);
    // layer 1
    sess_linear<<<BATCH, 128, 0, stream>>>(sbuf, w_sess + 1 * EMB * EMB, tbuf);
    sess_prop  <<<BATCH, 128, 0, stream>>>(DAb, tbuf, sbuf, acc2, out, 1);
}

// Round 2
// 740.917 us; speedup vs baseline: 6.7007x; 6.7007x over previous
//
#include <hip/hip_runtime.h>

#define N_NODE 100000
#define EMB 112
#define BATCH 512
#define SEQL 50
#define NNZ 1600000

#define SCAN_CHUNK 1024
#define SCAN_NBLK ((N_NODE + SCAN_CHUNK - 1) / SCAN_CHUNK)   // 98

// ---------------- CSR build ------------------------------------------------
__global__ __launch_bounds__(256) void csr_count(
    const int* __restrict__ rows, int* __restrict__ counts)
{
    int e = blockIdx.x * 256 + threadIdx.x;
    if (e < NNZ) atomicAdd(&counts[rows[e]], 1);
}

// scan1: per-1024-chunk exclusive scan (in place into row_start), chunk totals
__global__ __launch_bounds__(256) void csr_scan1(
    const int* __restrict__ counts, int* __restrict__ row_start,
    int* __restrict__ blk_sums)
{
    __shared__ int lsum[256];
    const int tid = threadIdx.x;
    const int base = blockIdx.x * SCAN_CHUNK + tid * 4;
    int local[4], s = 0;
    for (int j = 0; j < 4; ++j) {
        int idx = base + j;
        int v = (idx < N_NODE) ? counts[idx] : 0;
        local[j] = s;
        s += v;
    }
    lsum[tid] = s;
    __syncthreads();
    for (int off = 1; off < 256; off <<= 1) {
        int t = (tid >= off) ? lsum[tid - off] : 0;
        __syncthreads();
        lsum[tid] += t;
        __syncthreads();
    }
    int thread_excl = lsum[tid] - s;
    for (int j = 0; j < 4; ++j) {
        int idx = base + j;
        if (idx < N_NODE) row_start[idx] = thread_excl + local[j];
    }
    if (tid == 255) blk_sums[blockIdx.x] = lsum[255];
}

// scan2: single block, exclusive scan of the 98 chunk totals
__global__ __launch_bounds__(128) void csr_scan2(
    const int* __restrict__ blk_sums, int* __restrict__ blk_off)
{
    __shared__ int s[128];
    const int tid = threadIdx.x;
    int v = (tid < SCAN_NBLK) ? blk_sums[tid] : 0;
    s[tid] = v;
    __syncthreads();
    for (int off = 1; off < 128; off <<= 1) {
        int t = (tid >= off) ? s[tid - off] : 0;
        __syncthreads();
        s[tid] += t;
        __syncthreads();
    }
    if (tid < SCAN_NBLK) blk_off[tid] = s[tid] - v;
}

// scan3: add chunk offsets
__global__ __launch_bounds__(256) void csr_scan3(
    int* __restrict__ row_start, const int* __restrict__ blk_off)
{
    int idx = blockIdx.x * SCAN_CHUNK + threadIdx.x * 4;
    int off = blk_off[blockIdx.x];
    for (int j = 0; j < 4; ++j)
        if (idx + j < N_NODE) row_start[idx + j] += off;
}

__global__ __launch_bounds__(256) void csr_scatter(
    const int* __restrict__ rows, const int* __restrict__ cols,
    const float* __restrict__ vals, const int* __restrict__ row_start,
    int* __restrict__ cursor, int* __restrict__ csr_col,
    float* __restrict__ csr_val)
{
    int e = blockIdx.x * 256 + threadIdx.x;
    if (e >= NNZ) return;
    int r = rows[e];
    int slot = row_start[r] + atomicAdd(&cursor[r], 1);
    csr_col[slot] = cols[e];
    csr_val[slot] = vals[e];
}

// ---------------- HyperConv layer: segmented sum over CSR, no atomics ------
// out[r] = sum_{i in row r} csr_val[i] * src[csr_col[i]]
// One 128-thread block per row; lanes 0..111 own one feature each.
__global__ __launch_bounds__(128) void spmm_csr(
    const float* __restrict__ src, const int* __restrict__ csr_col,
    const float* __restrict__ csr_val, const int* __restrict__ row_start,
    const int* __restrict__ counts, float* __restrict__ out)
{
    const int row = blockIdx.x;
    const int d = threadIdx.x;
    const int beg = row_start[row];
    const int n = counts[row];
    float acc = 0.f;
    int i = 0;
    for (; i + 1 < n; i += 2) {
        int   c0 = csr_col[beg + i],     c1 = csr_col[beg + i + 1];
        float v0 = csr_val[beg + i],     v1 = csr_val[beg + i + 1];
        if (d < EMB) {
            acc += v0 * src[(size_t)c0 * EMB + d];
            acc += v1 * src[(size_t)c1 * EMB + d];
        }
    }
    if (i < n) {
        int c0 = csr_col[beg + i];
        float v0 = csr_val[beg + i];
        if (d < EMB) acc += v0 * src[(size_t)c0 * EMB + d];
    }
    if (d < EMB) out[(size_t)row * EMB + d] = acc;
}

// ---------------- Fused SR_IEM attention pooling ---------------------------
#define PAD 113
__global__ __launch_bounds__(256) void attention_pool(
    const float* __restrict__ emb0, const float* __restrict__ emb1,
    const float* __restrict__ emb2,
    const float* __restrict__ Wq, const float* __restrict__ Wk,
    const int* __restrict__ session_item, const int* __restrict__ session_len,
    const float* __restrict__ mask,
    float* __restrict__ seq_h, float* __restrict__ acc2)
{
    __shared__ float s_seq[SEQL][PAD];
    __shared__ float s_Q[SEQL][PAD];
    __shared__ float s_K[SEQL][PAD];
    __shared__ float s_alpha[SEQL];
    __shared__ float s_beta[SEQL];

    const int b = blockIdx.x;
    const int tid = threadIdx.x;

    for (int idx = tid; idx < SEQL * EMB; idx += 256) {
        int l = idx / EMB, d = idx - l * EMB;
        int g = session_item[b * SEQL + l];
        float v = 0.f;
        if (g > 0) {
            size_t off = (size_t)(g - 1) * EMB + d;
            v = (emb0[off] + emb1[off] + emb2[off]) * (1.f / 3.f);
        }
        s_seq[l][d] = v;
    }
    if (tid < SEQL) s_alpha[tid] = 0.f;
    __syncthreads();

    for (int idx = tid; idx < SEQL * EMB; idx += 256) {
        int l = idx / EMB, e = idx - l * EMB;
        float q = 0.f, k = 0.f;
        for (int d = 0; d < EMB; ++d) {
            float sv = s_seq[l][d];
            q += sv * Wq[d * EMB + e];
            k += sv * Wk[d * EMB + e];
        }
        s_Q[l][e] = 1.f / (1.f + __expf(-q));
        s_K[l][e] = 1.f / (1.f + __expf(-k));
    }
    __syncthreads();

    const float inv_sqrt_d = rsqrtf((float)EMB);
    for (int idx = tid; idx < SEQL * SEQL; idx += 256) {
        int m = idx / SEQL, l = idx - m * SEQL;
        if (l == m) continue;
        if (mask[b * SEQL + l] == 0.f || mask[b * SEQL + m] == 0.f) continue;
        float dot = 0.f;
        for (int d = 0; d < EMB; ++d) dot += s_Q[l][d] * s_K[m][d];
        float c = inv_sqrt_d / (1.f + __expf(-dot));
        atomicAdd(&s_alpha[l], c);
    }
    __syncthreads();

    if (tid < 64) {
        float slen = (float)session_len[b];
        float a = (tid < SEQL && mask[b * SEQL + tid] > 0.f)
                      ? s_alpha[tid] / slen : -1e30f;
        float mx = a;
        for (int o = 32; o > 0; o >>= 1) mx = fmaxf(mx, __shfl_xor(mx, o));
        float ex = __expf(a - mx);
        float sm = ex;
        for (int o = 32; o > 0; o >>= 1) sm += __shfl_xor(sm, o);
        if (tid < SEQL) s_beta[tid] = ex / sm;
    }
    __syncthreads();

    for (int d = tid; d < EMB; d += 256) {
        float h = 0.f;
        for (int l = 0; l < SEQL; ++l) h += s_beta[l] * s_seq[l][d];
        seq_h[b * EMB + d] = h;
        acc2[b * EMB + d] = h;
    }
}

// ---------------- DA = D @ A ----------------------------------------------
__global__ __launch_bounds__(256) void gemm_DA(
    const float* __restrict__ D, const float* __restrict__ A,
    float* __restrict__ DA)
{
    int j = blockIdx.x * 256 + threadIdx.x;
    int i = blockIdx.y;
    float acc = 0.f;
    for (int k = 0; k < BATCH; ++k) acc += D[i * BATCH + k] * A[k * BATCH + j];
    DA[i * BATCH + j] = acc;
}

// ---------------- t = s @ W^T ----------------------------------------------
__global__ __launch_bounds__(128) void sess_linear(
    const float* __restrict__ s, const float* __restrict__ W,
    float* __restrict__ t)
{
    __shared__ float s_row[EMB];
    int b = blockIdx.x;
    int e = threadIdx.x;
    if (e < EMB) s_row[e] = s[b * EMB + e];
    __syncthreads();
    if (e >= EMB) return;
    float acc = 0.f;
    for (int d = 0; d < EMB; ++d) acc += s_row[d] * W[e * EMB + d];
    t[b * EMB + e] = acc;
}

// ---------------- s = DA @ t; acc2 += s/||s||; last: out = acc2/3 ----------
__global__ __launch_bounds__(128) void sess_prop(
    const float* __restrict__ DA, const float* __restrict__ t,
    float* __restrict__ s_out, float* __restrict__ acc2,
    float* __restrict__ out, int is_last)
{
    __shared__ float s_da[BATCH];
    __shared__ float s_sq[128];
    int b = blockIdx.x;
    int e = threadIdx.x;
    for (int k = e; k < BATCH; k += 128) s_da[k] = DA[b * BATCH + k];
    __syncthreads();

    float v = 0.f;
    if (e < EMB) {
        for (int k = 0; k < BATCH; ++k) v += s_da[k] * t[k * EMB + e];
    }
    s_sq[e] = (e < EMB) ? v * v : 0.f;
    __syncthreads();
    for (int off = 64; off > 0; off >>= 1) {
        if (e < off) s_sq[e] += s_sq[e + off];
        __syncthreads();
    }
    float nrm = fmaxf(sqrtf(s_sq[0]), 1e-12f);
    if (e < EMB) {
        float a = acc2[b * EMB + e] + v / nrm;
        acc2[b * EMB + e] = a;
        s_out[b * EMB + e] = v;
        if (is_last) out[b * EMB + e] = a * (1.f / 3.f);
    }
}

extern "C" void kernel_launch(void* const* d_in, const int* in_sizes, int n_in,
                              void* d_out, int out_size, void* d_ws, size_t ws_size,
                              hipStream_t stream)
{
    (void)in_sizes; (void)n_in; (void)out_size; (void)ws_size;

    const float* embedding    = (const float*)d_in[0];
    const float* adj_vals     = (const float*)d_in[1];
    const float* W_q          = (const float*)d_in[2];
    const float* W_k          = (const float*)d_in[3];
    const float* w_sess       = (const float*)d_in[4];
    const float* D            = (const float*)d_in[5];
    const float* A            = (const float*)d_in[6];
    const int*   adj_rows     = (const int*)d_in[7];
    const int*   adj_cols     = (const int*)d_in[8];
    const int*   session_item = (const int*)d_in[9];
    const int*   session_len  = (const int*)d_in[10];
    const float* mask         = (const float*)d_in[11];
    float* out = (float*)d_out;

    // workspace layout (4-byte elems):
    float* emb1 = (float*)d_ws;                              // 11.2M
    float* emb2 = emb1 + (size_t)N_NODE * EMB;               // 11.2M
    float* DAb  = emb2 + (size_t)N_NODE * EMB;               // 256K
    float* seqh = DAb  + (size_t)BATCH * BATCH;              // 56K
    float* acc2 = seqh + (size_t)BATCH * EMB;                // 56K
    float* tbuf = acc2 + (size_t)BATCH * EMB;                // 56K
    float* sbuf = tbuf + (size_t)BATCH * EMB;                // 56K
    int*   counts    = (int*)(sbuf + (size_t)BATCH * EMB);   // 100K
    int*   row_start = counts + N_NODE;                      // 100K
    int*   cursor    = row_start + N_NODE;                   // 100K
    int*   blk_sums  = cursor + N_NODE;                      // 128
    int*   blk_off   = blk_sums + 128;                       // 128
    int*   csr_col   = blk_off + 128;                        // 1.6M
    float* csr_val   = (float*)(csr_col + NNZ);              // 1.6M

    // ---- build CSR (same work every call; graph-capture safe) ----
    hipMemsetAsync(counts, 0, N_NODE * sizeof(int), stream);
    hipMemsetAsync(cursor, 0, N_NODE * sizeof(int), stream);
    csr_count<<<(NNZ + 255) / 256, 256, 0, stream>>>(adj_rows, counts);
    csr_scan1<<<SCAN_NBLK, 256, 0, stream>>>(counts, row_start, blk_sums);
    csr_scan2<<<1, 128, 0, stream>>>(blk_sums, blk_off);
    csr_scan3<<<SCAN_NBLK, 256, 0, stream>>>(row_start, blk_off);
    csr_scatter<<<(NNZ + 255) / 256, 256, 0, stream>>>(adj_rows, adj_cols, adj_vals,
                                                       row_start, cursor, csr_col, csr_val);

    // ---- 2 hyperconv layers, no atomics ----
    spmm_csr<<<N_NODE, 128, 0, stream>>>(embedding, csr_col, csr_val, row_start, counts, emb1);
    spmm_csr<<<N_NODE, 128, 0, stream>>>(emb1,      csr_col, csr_val, row_start, counts, emb2);

    attention_pool<<<BATCH, 256, 0, stream>>>(embedding, emb1, emb2, W_q, W_k,
                                              session_item, session_len, mask,
                                              seqh, acc2);

    gemm_DA<<<dim3(BATCH / 256, BATCH), 256, 0, stream>>>(D, A, DAb);

    sess_linear<<<BATCH, 128, 0, stream>>>(seqh, w_sess + 0 * EMB * EMB, tbuf);
    sess_prop  <<<BATCH, 128, 0, stream>>>(DAb, tbuf, sbuf, acc2, out, 0);
    sess_linear<<<BATCH, 128, 0, stream>>>(sbuf, w_sess + 1 * EMB * EMB, tbuf);
    sess_prop  <<<BATCH, 128, 0, stream>>>(DAb, tbuf, sbuf, acc2, out, 1);
}

// Round 3
// 574.593 us; speedup vs baseline: 8.6404x; 1.2895x over previous
//
#include <hip/hip_runtime.h>

#define N_NODE 100000
#define EMB 112
#define BATCH 512
#define SEQL 50
#define NNZ 1600000
#define NROWS (BATCH * SEQL)          // 25600 flattened session slots

#define SCAN_CHUNK 1024
#define SCAN_NBLK ((N_NODE + SCAN_CHUNK - 1) / SCAN_CHUNK)   // 98

// ---------------- CSR build ------------------------------------------------
__global__ __launch_bounds__(256) void csr_count(
    const int* __restrict__ rows, int* __restrict__ counts)
{
    int e = blockIdx.x * 256 + threadIdx.x;
    if (e < NNZ) atomicAdd(&counts[rows[e]], 1);
}

__global__ __launch_bounds__(256) void csr_scan1(
    const int* __restrict__ counts, int* __restrict__ row_start,
    int* __restrict__ blk_sums)
{
    __shared__ int lsum[256];
    const int tid = threadIdx.x;
    const int base = blockIdx.x * SCAN_CHUNK + tid * 4;
    int local[4], s = 0;
    for (int j = 0; j < 4; ++j) {
        int idx = base + j;
        int v = (idx < N_NODE) ? counts[idx] : 0;
        local[j] = s;
        s += v;
    }
    lsum[tid] = s;
    __syncthreads();
    for (int off = 1; off < 256; off <<= 1) {
        int t = (tid >= off) ? lsum[tid - off] : 0;
        __syncthreads();
        lsum[tid] += t;
        __syncthreads();
    }
    int thread_excl = lsum[tid] - s;
    for (int j = 0; j < 4; ++j) {
        int idx = base + j;
        if (idx < N_NODE) row_start[idx] = thread_excl + local[j];
    }
    if (tid == 255) blk_sums[blockIdx.x] = lsum[255];
}

__global__ __launch_bounds__(128) void csr_scan2(
    const int* __restrict__ blk_sums, int* __restrict__ blk_off)
{
    __shared__ int s[128];
    const int tid = threadIdx.x;
    int v = (tid < SCAN_NBLK) ? blk_sums[tid] : 0;
    s[tid] = v;
    __syncthreads();
    for (int off = 1; off < 128; off <<= 1) {
        int t = (tid >= off) ? s[tid - off] : 0;
        __syncthreads();
        s[tid] += t;
        __syncthreads();
    }
    if (tid < SCAN_NBLK) blk_off[tid] = s[tid] - v;
}

__global__ __launch_bounds__(256) void csr_scan3(
    int* __restrict__ row_start, const int* __restrict__ blk_off)
{
    int idx = blockIdx.x * SCAN_CHUNK + threadIdx.x * 4;
    int off = blk_off[blockIdx.x];
    for (int j = 0; j < 4; ++j)
        if (idx + j < N_NODE) row_start[idx + j] += off;
}

__global__ __launch_bounds__(256) void csr_scatter(
    const int* __restrict__ rows, const int* __restrict__ cols,
    const float* __restrict__ vals, const int* __restrict__ row_start,
    int* __restrict__ cursor, int* __restrict__ csr_col,
    float* __restrict__ csr_val)
{
    int e = blockIdx.x * 256 + threadIdx.x;
    if (e >= NNZ) return;
    int r = rows[e];
    int slot = row_start[r] + atomicAdd(&cursor[r], 1);
    csr_col[slot] = cols[e];
    csr_val[slot] = vals[e];
}

// mark rows of the embedding table that attention will actually read
__global__ __launch_bounds__(256) void mark_needed(
    const int* __restrict__ items, int* __restrict__ needed)
{
    int i = blockIdx.x * 256 + threadIdx.x;
    if (i >= NROWS) return;
    int g = items[i];
    if (g > 0) needed[g - 1] = 1;     // benign races, all write 1
}

// ---------------- HyperConv layer: wave-per-row segmented sum --------------
// lanes 0..55 each own a float2 feature chunk (112 floats). 4 rows per block.
__global__ __launch_bounds__(256) void spmm_csr(
    const float* __restrict__ src, const int* __restrict__ csr_col,
    const float* __restrict__ csr_val, const int* __restrict__ row_start,
    const int* __restrict__ counts, const int* __restrict__ needed,
    int use_needed, float* __restrict__ out)
{
    const int wave = threadIdx.x >> 6;
    const int lane = threadIdx.x & 63;
    const int row = blockIdx.x * 4 + wave;
    if (row >= N_NODE) return;
    if (use_needed && needed[row] == 0) return;   // wave-uniform exit
    const int beg = row_start[row];
    const int n = counts[row];
    const bool act = lane < 56;
    const int d = lane * 2;
    float ax = 0.f, ay = 0.f;
    int i = 0;
    for (; i + 4 <= n; i += 4) {
        int   c0 = csr_col[beg + i],     c1 = csr_col[beg + i + 1];
        int   c2 = csr_col[beg + i + 2], c3 = csr_col[beg + i + 3];
        float v0 = csr_val[beg + i],     v1 = csr_val[beg + i + 1];
        float v2 = csr_val[beg + i + 2], v3 = csr_val[beg + i + 3];
        if (act) {
            float2 x0 = *(const float2*)(src + (size_t)c0 * EMB + d);
            float2 x1 = *(const float2*)(src + (size_t)c1 * EMB + d);
            float2 x2 = *(const float2*)(src + (size_t)c2 * EMB + d);
            float2 x3 = *(const float2*)(src + (size_t)c3 * EMB + d);
            ax += v0 * x0.x; ay += v0 * x0.y;
            ax += v1 * x1.x; ay += v1 * x1.y;
            ax += v2 * x2.x; ay += v2 * x2.y;
            ax += v3 * x3.x; ay += v3 * x3.y;
        }
    }
    for (; i < n; ++i) {
        int c0 = csr_col[beg + i];
        float v0 = csr_val[beg + i];
        if (act) {
            float2 x0 = *(const float2*)(src + (size_t)c0 * EMB + d);
            ax += v0 * x0.x; ay += v0 * x0.y;
        }
    }
    if (act) {
        float2 r; r.x = ax; r.y = ay;
        *(float2*)(out + (size_t)row * EMB + d) = r;
    }
}

// ---------------- gather + Q/K projection (register-tiled) -----------------
// 32 seq rows per block; thread t<224: 4 rows x 4 cols of Q and K.
#define GP_ROWS 32
#define SEQ_PAD 116   // floats; keeps float4 alignment, odd/32 bank spread
__global__ __launch_bounds__(256) void gather_project(
    const float* __restrict__ emb0, const float* __restrict__ emb1,
    const float* __restrict__ emb2,
    const int* __restrict__ items,
    const float* __restrict__ Wq, const float* __restrict__ Wk,
    float* __restrict__ seqws, float* __restrict__ Qws, float* __restrict__ Kws)
{
    __shared__ float s_seq[GP_ROWS][SEQ_PAD];
    const int t = threadIdx.x;
    const int R0 = blockIdx.x * GP_ROWS;

    // gather seq rows (and persist for the pooling kernel)
    for (int idx = t; idx < GP_ROWS * EMB; idx += 256) {
        int r = idx / EMB, d = idx - r * EMB;
        int g = items[R0 + r];
        float v = 0.f;
        if (g > 0) {
            size_t off = (size_t)(g - 1) * EMB + d;
            v = (emb0[off] + emb1[off] + emb2[off]) * (1.f / 3.f);
        }
        s_seq[r][d] = v;
        seqws[(size_t)(R0 + r) * EMB + d] = v;
    }
    __syncthreads();

    if (t >= 224) return;
    const int rg = t / 28;          // 0..7 -> 4 rows each
    const int e0 = (t % 28) * 4;    // 4 output cols

    float accq[4][4] = {{0.f}}, acck[4][4] = {{0.f}};
    for (int d4 = 0; d4 < 28; ++d4) {
        float sa[4][4];
        #pragma unroll
        for (int rr = 0; rr < 4; ++rr) {
            float4 v = *(const float4*)&s_seq[rg * 4 + rr][d4 * 4];
            sa[rr][0] = v.x; sa[rr][1] = v.y; sa[rr][2] = v.z; sa[rr][3] = v.w;
        }
        #pragma unroll
        for (int j = 0; j < 4; ++j) {
            const int d = d4 * 4 + j;
            float4 wq = *(const float4*)&Wq[d * EMB + e0];
            float4 wk = *(const float4*)&Wk[d * EMB + e0];
            #pragma unroll
            for (int rr = 0; rr < 4; ++rr) {
                float s = sa[rr][j];
                accq[rr][0] += s * wq.x; accq[rr][1] += s * wq.y;
                accq[rr][2] += s * wq.z; accq[rr][3] += s * wq.w;
                acck[rr][0] += s * wk.x; acck[rr][1] += s * wk.y;
                acck[rr][2] += s * wk.z; acck[rr][3] += s * wk.w;
            }
        }
    }
    #pragma unroll
    for (int rr = 0; rr < 4; ++rr) {
        size_t o = (size_t)(R0 + rg * 4 + rr) * EMB + e0;
        float4 q, k;
        q.x = 1.f / (1.f + __expf(-accq[rr][0]));
        q.y = 1.f / (1.f + __expf(-accq[rr][1]));
        q.z = 1.f / (1.f + __expf(-accq[rr][2]));
        q.w = 1.f / (1.f + __expf(-accq[rr][3]));
        k.x = 1.f / (1.f + __expf(-acck[rr][0]));
        k.y = 1.f / (1.f + __expf(-acck[rr][1]));
        k.z = 1.f / (1.f + __expf(-acck[rr][2]));
        k.w = 1.f / (1.f + __expf(-acck[rr][3]));
        *(float4*)&Qws[o] = q;
        *(float4*)&Kws[o] = k;
    }
}

// ---------------- scores + softmax + pooling (no LDS atomics) --------------
__global__ __launch_bounds__(256) void attn_score_pool(
    const float* __restrict__ Qws, const float* __restrict__ Kws,
    const float* __restrict__ seqws,
    const int* __restrict__ session_len, const float* __restrict__ mask,
    float* __restrict__ seq_h, float* __restrict__ acc2)
{
    __shared__ float sQ[SEQL][SEQ_PAD];
    __shared__ float sK[SEQL][SEQ_PAD];
    __shared__ float s_part[SEQL][4];
    __shared__ float s_mask[SEQL];
    __shared__ float s_beta[SEQL];

    const int b = blockIdx.x;
    const int t = threadIdx.x;

    for (int idx = t; idx < SEQL * (EMB / 4); idx += 256) {
        int l = idx / (EMB / 4), d4 = idx - l * (EMB / 4);
        *(float4*)&sQ[l][d4 * 4] = *(const float4*)&Qws[((size_t)b * SEQL + l) * EMB + d4 * 4];
        *(float4*)&sK[l][d4 * 4] = *(const float4*)&Kws[((size_t)b * SEQL + l) * EMB + d4 * 4];
    }
    if (t < SEQL) s_mask[t] = mask[b * SEQL + t];
    __syncthreads();

    const float inv_sqrt_d = rsqrtf((float)EMB);
    if (t < 200) {
        const int l = t >> 2;
        const int m0 = t & 3;
        float partial = 0.f;
        if (s_mask[l] != 0.f) {
            for (int m = m0; m < SEQL; m += 4) {
                if (m == l || s_mask[m] == 0.f) continue;
                float dot = 0.f;
                for (int d4 = 0; d4 < EMB / 4; ++d4) {
                    float4 a = *(const float4*)&sQ[l][d4 * 4];
                    float4 c = *(const float4*)&sK[m][d4 * 4];
                    dot += a.x * c.x + a.y * c.y + a.z * c.z + a.w * c.w;
                }
                partial += inv_sqrt_d / (1.f + __expf(-dot));
            }
        }
        s_part[l][m0] = partial;
    }
    __syncthreads();

    if (t < 64) {
        float slen = (float)session_len[b];
        float a = -1e30f;
        if (t < SEQL && s_mask[t] > 0.f)
            a = (s_part[t][0] + s_part[t][1] + s_part[t][2] + s_part[t][3]) / slen;
        float mx = a;
        for (int o = 32; o > 0; o >>= 1) mx = fmaxf(mx, __shfl_xor(mx, o));
        float ex = __expf(a - mx);
        float sm = ex;
        for (int o = 32; o > 0; o >>= 1) sm += __shfl_xor(sm, o);
        if (t < SEQL) s_beta[t] = ex / sm;
    }
    __syncthreads();

    if (t < EMB) {
        float h = 0.f;
        for (int l = 0; l < SEQL; ++l)
            h += s_beta[l] * seqws[((size_t)b * SEQL + l) * EMB + t];
        seq_h[b * EMB + t] = h;
        acc2[b * EMB + t] = h;
    }
}

// ---------------- DA = D @ A  (32x32 LDS-tiled) ----------------------------
__global__ __launch_bounds__(256) void gemm_DA(
    const float* __restrict__ D, const float* __restrict__ A,
    float* __restrict__ DA)
{
    __shared__ float sD[32][33];
    __shared__ float sA[32][33];
    const int tx = threadIdx.x & 15;
    const int ty = threadIdx.x >> 4;
    const int i0 = blockIdx.y * 32;
    const int j0 = blockIdx.x * 32;
    float a00 = 0.f, a01 = 0.f, a10 = 0.f, a11 = 0.f;
    for (int k0 = 0; k0 < BATCH; k0 += 32) {
        for (int idx = threadIdx.x; idx < 1024; idx += 256) {
            int r = idx >> 5, c = idx & 31;
            sD[r][c] = D[(i0 + r) * BATCH + k0 + c];
            sA[r][c] = A[(k0 + r) * BATCH + j0 + c];
        }
        __syncthreads();
        #pragma unroll 8
        for (int kk = 0; kk < 32; ++kk) {
            float d0 = sD[2 * ty][kk], d1 = sD[2 * ty + 1][kk];
            float b0 = sA[kk][2 * tx], b1 = sA[kk][2 * tx + 1];
            a00 += d0 * b0; a01 += d0 * b1;
            a10 += d1 * b0; a11 += d1 * b1;
        }
        __syncthreads();
    }
    DA[(i0 + 2 * ty) * BATCH + j0 + 2 * tx] = a00;
    DA[(i0 + 2 * ty) * BATCH + j0 + 2 * tx + 1] = a01;
    DA[(i0 + 2 * ty + 1) * BATCH + j0 + 2 * tx] = a10;
    DA[(i0 + 2 * ty + 1) * BATCH + j0 + 2 * tx + 1] = a11;
}

// ---------------- t = s @ W^T ----------------------------------------------
__global__ __launch_bounds__(128) void sess_linear(
    const float* __restrict__ s, const float* __restrict__ W,
    float* __restrict__ t)
{
    __shared__ float s_row[EMB];
    int b = blockIdx.x;
    int e = threadIdx.x;
    if (e < EMB) s_row[e] = s[b * EMB + e];
    __syncthreads();
    if (e >= EMB) return;
    float acc = 0.f;
    for (int d = 0; d < EMB; ++d) acc += s_row[d] * W[e * EMB + d];
    t[b * EMB + e] = acc;
}

// ---------------- s = DA @ t; acc2 += s/||s||; last: out = acc2/3 ----------
__global__ __launch_bounds__(128) void sess_prop(
    const float* __restrict__ DA, const float* __restrict__ t,
    float* __restrict__ s_out, float* __restrict__ acc2,
    float* __restrict__ out, int is_last)
{
    __shared__ float s_da[BATCH];
    __shared__ float s_sq[128];
    int b = blockIdx.x;
    int e = threadIdx.x;
    for (int k = e; k < BATCH; k += 128) s_da[k] = DA[b * BATCH + k];
    __syncthreads();

    float v = 0.f;
    if (e < EMB) {
        for (int k = 0; k < BATCH; ++k) v += s_da[k] * t[k * EMB + e];
    }
    s_sq[e] = (e < EMB) ? v * v : 0.f;
    __syncthreads();
    for (int off = 64; off > 0; off >>= 1) {
        if (e < off) s_sq[e] += s_sq[e + off];
        __syncthreads();
    }
    float nrm = fmaxf(sqrtf(s_sq[0]), 1e-12f);
    if (e < EMB) {
        float a = acc2[b * EMB + e] + v / nrm;
        acc2[b * EMB + e] = a;
        s_out[b * EMB + e] = v;
        if (is_last) out[b * EMB + e] = a * (1.f / 3.f);
    }
}

extern "C" void kernel_launch(void* const* d_in, const int* in_sizes, int n_in,
                              void* d_out, int out_size, void* d_ws, size_t ws_size,
                              hipStream_t stream)
{
    (void)in_sizes; (void)n_in; (void)out_size; (void)ws_size;

    const float* embedding    = (const float*)d_in[0];
    const float* adj_vals     = (const float*)d_in[1];
    const float* W_q          = (const float*)d_in[2];
    const float* W_k          = (const float*)d_in[3];
    const float* w_sess       = (const float*)d_in[4];
    const float* D            = (const float*)d_in[5];
    const float* A            = (const float*)d_in[6];
    const int*   adj_rows     = (const int*)d_in[7];
    const int*   adj_cols     = (const int*)d_in[8];
    const int*   session_item = (const int*)d_in[9];
    const int*   session_len  = (const int*)d_in[10];
    const float* mask         = (const float*)d_in[11];
    float* out = (float*)d_out;

    // ---- workspace layout (4-byte elems) ----
    float* emb1      = (float*)d_ws;
    float* emb2      = emb1 + (size_t)N_NODE * EMB;
    float* DAb       = emb2 + (size_t)N_NODE * EMB;
    float* seqh      = DAb  + (size_t)BATCH * BATCH;
    float* acc2      = seqh + (size_t)BATCH * EMB;
    float* tbuf      = acc2 + (size_t)BATCH * EMB;
    float* sbuf      = tbuf + (size_t)BATCH * EMB;
    float* seqws     = sbuf + (size_t)BATCH * EMB;
    float* Qws       = seqws + (size_t)NROWS * EMB;
    float* Kws       = Qws   + (size_t)NROWS * EMB;
    int*   counts    = (int*)(Kws + (size_t)NROWS * EMB);
    int*   cursor    = counts + N_NODE;
    int*   needed    = cursor + N_NODE;
    int*   row_start = needed + N_NODE;
    int*   blk_sums  = row_start + N_NODE;
    int*   blk_off   = blk_sums + 128;
    int*   csr_col   = blk_off + 128;
    float* csr_val   = (float*)(csr_col + NNZ);

    // counts, cursor, needed are contiguous -> one memset
    hipMemsetAsync(counts, 0, (size_t)3 * N_NODE * sizeof(int), stream);

    // ---- build CSR ----
    csr_count<<<(NNZ + 255) / 256, 256, 0, stream>>>(adj_rows, counts);
    csr_scan1<<<SCAN_NBLK, 256, 0, stream>>>(counts, row_start, blk_sums);
    csr_scan2<<<1, 128, 0, stream>>>(blk_sums, blk_off);
    csr_scan3<<<SCAN_NBLK, 256, 0, stream>>>(row_start, blk_off);
    csr_scatter<<<(NNZ + 255) / 256, 256, 0, stream>>>(adj_rows, adj_cols, adj_vals,
                                                       row_start, cursor, csr_col, csr_val);
    mark_needed<<<(NROWS + 255) / 256, 256, 0, stream>>>(session_item, needed);

    // ---- hyperconv: layer1 all rows, layer2 only rows attention reads ----
    const int spmm_grid = (N_NODE + 3) / 4;
    spmm_csr<<<spmm_grid, 256, 0, stream>>>(embedding, csr_col, csr_val, row_start,
                                            counts, needed, 0, emb1);
    spmm_csr<<<spmm_grid, 256, 0, stream>>>(emb1, csr_col, csr_val, row_start,
                                            counts, needed, 1, emb2);

    // ---- attention ----
    gather_project<<<NROWS / GP_ROWS, 256, 0, stream>>>(embedding, emb1, emb2,
                                                        session_item, W_q, W_k,
                                                        seqws, Qws, Kws);
    attn_score_pool<<<BATCH, 256, 0, stream>>>(Qws, Kws, seqws, session_len, mask,
                                               seqh, acc2);

    // ---- session graph ----
    gemm_DA<<<dim3(16, 16), 256, 0, stream>>>(D, A, DAb);
    sess_linear<<<BATCH, 128, 0, stream>>>(seqh, w_sess + 0 * EMB * EMB, tbuf);
    sess_prop  <<<BATCH, 128, 0, stream>>>(DAb, tbuf, sbuf, acc2, out, 0);
    sess_linear<<<BATCH, 128, 0, stream>>>(sbuf, w_sess + 1 * EMB * EMB, tbuf);
    sess_prop  <<<BATCH, 128, 0, stream>>>(DAb, tbuf, sbuf, acc2, out, 1);
}